// Round 3
// baseline (637.140 us; speedup 1.0000x reference)
//
#include <hip/hip_runtime.h>
#include <math.h>

// ---------------- problem constants ----------------
constexpr int N_A   = 16384;
constexpr int N_P   = 16384;
constexpr int IN_D  = 128;
constexpr int HID   = 64;
constexpr int NH    = 4;    // heads
constexpr int OUTD  = 349;
constexpr int NE    = 262144; // edges per type (2^18)
constexpr float NEG = 0.2f;

__device__ __forceinline__ float lrelu(float x) { return x > 0.f ? x : NEG * x; }

// ---------------- kernel 1: ntype scaling ----------------
__global__ __launch_bounds__(256) void k_scale(const float* __restrict__ xa,
                                               const float* __restrict__ xp,
                                               const float* __restrict__ nt,
                                               float* __restrict__ ha,
                                               float* __restrict__ hp) {
    int i4 = blockIdx.x * 256 + threadIdx.x;           // one float4 each
    if (i4 >= N_A * IN_D / 4) return;
    int col4 = i4 & (IN_D / 4 - 1);
    float4 sa = ((const float4*)nt)[col4];
    float4 sp = ((const float4*)nt)[IN_D / 4 + col4];
    float4 a = ((const float4*)xa)[i4];
    a.x *= sa.x; a.y *= sa.y; a.z *= sa.z; a.w *= sa.w;
    ((float4*)ha)[i4] = a;
    float4 p = ((const float4*)xp)[i4];
    p.x *= sp.x; p.y *= sp.y; p.z *= sp.z; p.w *= sp.w;
    ((float4*)hp)[i4] = p;
}

// ---------------- CSR build (once per call; edge lists shared by both layers)
__global__ __launch_bounds__(256) void k_zero(int* __restrict__ cnt) {
    int i = blockIdx.x * 256 + threadIdx.x;
    if (i < 3 * 16384) cnt[i] = 0;
}

__global__ __launch_bounds__(256) void k_hist(const int* __restrict__ dW, const int* __restrict__ dC,
                                              const int* __restrict__ dR, int* __restrict__ cnt) {
    int idx = blockIdx.x * 256 + threadIdx.x;   // 3*NE
    int t = idx >> 18, i = idx & (NE - 1);
    const int* d = t == 0 ? dW : t == 1 ? dC : dR;
    atomicAdd(cnt + t * 16384 + d[i], 1);
}

__global__ __launch_bounds__(1024) void k_scan(const int* __restrict__ cnt, int* __restrict__ row,
                                               int* __restrict__ cur) {
    int b = blockIdx.x;                          // type
    const int* c = cnt + b * 16384;
    int* r = row + b * 16385;
    int* q = cur + b * 16384;
    __shared__ int part[1024];
    int t = threadIdx.x;
    int loc[16], s = 0;
#pragma unroll
    for (int i = 0; i < 16; ++i) { loc[i] = s; s += c[t * 16 + i]; }
    part[t] = s;
    __syncthreads();
    for (int w = 1; w < 1024; w <<= 1) {
        int v = (t >= w) ? part[t - w] : 0;
        __syncthreads();
        part[t] += v;
        __syncthreads();
    }
    int off = (t > 0) ? part[t - 1] : 0;
#pragma unroll
    for (int i = 0; i < 16; ++i) {
        int v = off + loc[i];
        r[t * 16 + i] = v;
        q[t * 16 + i] = v;
    }
    if (t == 1023) r[16384] = part[1023];
}

__global__ __launch_bounds__(256) void k_scatter(const int* __restrict__ sW, const int* __restrict__ dW,
                                                 const int* __restrict__ sC, const int* __restrict__ dC,
                                                 const int* __restrict__ sR, const int* __restrict__ dR,
                                                 int* __restrict__ cur,
                                                 int* __restrict__ eW, int* __restrict__ eC,
                                                 int* __restrict__ eR) {
    int idx = blockIdx.x * 256 + threadIdx.x;   // 3*NE
    int t = idx >> 18, i = idx & (NE - 1);
    const int* sp = t == 0 ? sW : t == 1 ? sC : sR;
    const int* dp = t == 0 ? dW : t == 1 ? dC : dR;
    int* ep = t == 0 ? eW : t == 1 ? eC : eR;
    int pos = atomicAdd(cur + t * 16384 + dp[i], 1);
    ep[pos] = sp[i];
}

// ---------------- batched GEMM (X@W) + el/er head reductions -------
// Pointers passed as a struct but indexed ONLY with compile-time constants
// (runtime-indexed kernarg arrays alloca to scratch -> 400 MB spill traffic,
//  VGPR=256, occupancy 9.6% — measured round 2).
struct GemmJobs {
    const float* X[5];  const float* W[5];
    float* F[5];        float* EL[5];       float* ER[5];
    const float* AL[5]; const float* AR[5];
};

template <int K, int RELU>
__global__ __launch_bounds__(256) void k_gemm(GemmJobs j) {
    constexpr int RT = 128;                       // rows per block
    __shared__ float Wl[K * 64];
    __shared__ float Xl[RT][33];                  // 32-col K chunk, +1 pad

    const float* __restrict__ X;  const float* __restrict__ Wp;
    float* __restrict__ F;  float* __restrict__ EL;  float* __restrict__ ER;
    const float* __restrict__ AL; const float* __restrict__ AR;
    switch (blockIdx.z) {                         // block-uniform, static indices
      case 0: X=j.X[0]; Wp=j.W[0]; F=j.F[0]; EL=j.EL[0]; ER=j.ER[0]; AL=j.AL[0]; AR=j.AR[0]; break;
      case 1: X=j.X[1]; Wp=j.W[1]; F=j.F[1]; EL=j.EL[1]; ER=j.ER[1]; AL=j.AL[1]; AR=j.AR[1]; break;
      case 2: X=j.X[2]; Wp=j.W[2]; F=j.F[2]; EL=j.EL[2]; ER=j.ER[2]; AL=j.AL[2]; AR=j.AR[2]; break;
      case 3: X=j.X[3]; Wp=j.W[3]; F=j.F[3]; EL=j.EL[3]; ER=j.ER[3]; AL=j.AL[3]; AR=j.AR[3]; break;
      default: X=j.X[4]; Wp=j.W[4]; F=j.F[4]; EL=j.EL[4]; ER=j.ER[4]; AL=j.AL[4]; AR=j.AR[4]; break;
    }

    const int tid = threadIdx.x;
    const int r0 = blockIdx.x * RT;

    for (int idx = tid * 4; idx < K * 64; idx += 1024)
        *(float4*)(Wl + idx) = *(const float4*)(Wp + idx);

    const int rg = tid >> 2;      // 0..63  -> rows rg*2, rg*2+1
    const int h  = tid & 3;       // head / 16-col group
    float acc[2][16] = {{0.f}};

    for (int kc = 0; kc < K; kc += 32) {
        __syncthreads();
        for (int idx = tid * 4; idx < RT * 32; idx += 1024) {
            int row = idx >> 5, col = idx & 31;
            float4 v = *(const float4*)(X + (size_t)(r0 + row) * K + kc + col);
            if (RELU) {
                v.x = fmaxf(v.x, 0.f); v.y = fmaxf(v.y, 0.f);
                v.z = fmaxf(v.z, 0.f); v.w = fmaxf(v.w, 0.f);
            }
            Xl[row][col] = v.x; Xl[row][col + 1] = v.y;
            Xl[row][col + 2] = v.z; Xl[row][col + 3] = v.w;
        }
        __syncthreads();
        for (int kk = 0; kk < 32; ++kk) {
            float a0 = Xl[rg * 2][kk];
            float a1 = Xl[rg * 2 + 1][kk];
            const float4* wr = (const float4*)(Wl + (kc + kk) * 64 + h * 16);
#pragma unroll
            for (int q = 0; q < 4; ++q) {
                float4 w = wr[q];
                acc[0][q * 4 + 0] += a0 * w.x; acc[0][q * 4 + 1] += a0 * w.y;
                acc[0][q * 4 + 2] += a0 * w.z; acc[0][q * 4 + 3] += a0 * w.w;
                acc[1][q * 4 + 0] += a1 * w.x; acc[1][q * 4 + 1] += a1 * w.y;
                acc[1][q * 4 + 2] += a1 * w.z; acc[1][q * 4 + 3] += a1 * w.w;
            }
        }
    }

#pragma unroll
    for (int rr = 0; rr < 2; ++rr) {
        size_t n = (size_t)r0 + rg * 2 + rr;
        if (F) {
            float4* dst = (float4*)(F + n * 64 + h * 16);
            dst[0] = make_float4(acc[rr][0],  acc[rr][1],  acc[rr][2],  acc[rr][3]);
            dst[1] = make_float4(acc[rr][4],  acc[rr][5],  acc[rr][6],  acc[rr][7]);
            dst[2] = make_float4(acc[rr][8],  acc[rr][9],  acc[rr][10], acc[rr][11]);
            dst[3] = make_float4(acc[rr][12], acc[rr][13], acc[rr][14], acc[rr][15]);
        }
        if (EL) {
            const float* al = AL + h * 16;
            float s = 0.f;
#pragma unroll
            for (int q = 0; q < 16; ++q) s += acc[rr][q] * al[q];
            EL[n * 4 + h] = s;
        }
        if (ER) {
            const float* ar = AR + h * 16;
            float s = 0.f;
#pragma unroll
            for (int q = 0; q < 16; ++q) s += acc[rr][q] * ar[q];
            ER[n * 4 + h] = s;
        }
    }
}

// ---------------- per-destination gather aggregation (no atomics) ----------
struct AggType { const int* row; const int* es; const float* el; const float* er; const float* fs; };
struct AggArgs { AggType t[3]; const float* b; float* op; float* oa; };

__device__ __forceinline__ float agg_one(const int* __restrict__ rowv, const int* __restrict__ es,
                                         const float* __restrict__ el, const float* __restrict__ er,
                                         const float* __restrict__ fs, int d, int lane, int h) {
    int start = rowv[d], end = rowv[d + 1];
    if (end <= start) return 0.f;
    float4 r4 = *(const float4*)(er + (size_t)d * 4);
    // ---- phase A: per-head max over incident edges (lane-strided) ----
    float4 m4 = make_float4(-INFINITY, -INFINITY, -INFINITY, -INFINITY);
    for (int e = start + lane; e < end; e += 64) {
        int sn = es[e];
        float4 l4 = *(const float4*)(el + (size_t)sn * 4);
        m4.x = fmaxf(m4.x, lrelu(l4.x + r4.x));
        m4.y = fmaxf(m4.y, lrelu(l4.y + r4.y));
        m4.z = fmaxf(m4.z, lrelu(l4.z + r4.z));
        m4.w = fmaxf(m4.w, lrelu(l4.w + r4.w));
    }
#pragma unroll
    for (int w = 1; w < 64; w <<= 1) {
        m4.x = fmaxf(m4.x, __shfl_xor(m4.x, w, 64));
        m4.y = fmaxf(m4.y, __shfl_xor(m4.y, w, 64));
        m4.z = fmaxf(m4.z, __shfl_xor(m4.z, w, 64));
        m4.w = fmaxf(m4.w, __shfl_xor(m4.w, w, 64));
    }
    // ---- phase A2: denominator ----
    float4 s4 = make_float4(0.f, 0.f, 0.f, 0.f);
    for (int e = start + lane; e < end; e += 64) {
        int sn = es[e];
        float4 l4 = *(const float4*)(el + (size_t)sn * 4);
        s4.x += __expf(lrelu(l4.x + r4.x) - m4.x);
        s4.y += __expf(lrelu(l4.y + r4.y) - m4.y);
        s4.z += __expf(lrelu(l4.z + r4.z) - m4.z);
        s4.w += __expf(lrelu(l4.w + r4.w) - m4.w);
    }
#pragma unroll
    for (int w = 1; w < 64; w <<= 1) {
        s4.x += __shfl_xor(s4.x, w, 64);
        s4.y += __shfl_xor(s4.y, w, 64);
        s4.z += __shfl_xor(s4.z, w, 64);
        s4.w += __shfl_xor(s4.w, w, 64);
    }
    float mh = h == 0 ? m4.x : h == 1 ? m4.y : h == 2 ? m4.z : m4.w;
    float dh = h == 0 ? s4.x : h == 1 ? s4.y : h == 2 ? s4.z : s4.w;
    float rh = h == 0 ? r4.x : h == 1 ? r4.y : h == 2 ? r4.z : r4.w;
    float inv = 1.f / fmaxf(dh, 1e-9f);
    // ---- phase B: weighted feature accumulation; lane owns one column ----
    float acc = 0.f;
    for (int e = start; e < end; ++e) {
        int sn = es[e];                             // uniform across wave
        float a = __expf(lrelu(el[(size_t)sn * 4 + h] + rh) - mh) * inv;
        acc = fmaf(a, fs[(size_t)sn * 64 + lane], acc);
    }
    return acc;
}

__global__ __launch_bounds__(256) void k_agg(AggArgs A) {
    int wid = (blockIdx.x * 256 + threadIdx.x) >> 6;  // one wave per dst node
    int lane = threadIdx.x & 63;
    int h = lane >> 4;
    if (wid < N_P) {
        // paper node: writes-GAT + cites-GAT (+ both biases)
        float acc = A.b[lane] + A.b[64 + lane];
        acc += agg_one(A.t[0].row, A.t[0].es, A.t[0].el, A.t[0].er, A.t[0].fs, wid, lane, h);
        acc += agg_one(A.t[1].row, A.t[1].es, A.t[1].el, A.t[1].er, A.t[1].fs, wid, lane, h);
        A.op[(size_t)wid * 64 + lane] = acc;
    } else {
        int d = wid - N_P;
        float acc = A.b[128 + lane];
        acc += agg_one(A.t[2].row, A.t[2].es, A.t[2].el, A.t[2].er, A.t[2].fs, d, lane, h);
        A.oa[(size_t)d * 64 + lane] = acc;
    }
}

// ---------------- hf build: h2 = h1 + C, row l2-normalize, concat ------------
__global__ __launch_bounds__(256) void k_hf(const float* __restrict__ h1, float* __restrict__ hf,
                                            const float* __restrict__ ln1gb,
                                            const float* __restrict__ aw, const float* __restrict__ ab,
                                            const float* __restrict__ ln2gb,
                                            const float* __restrict__ fw1, const float* __restrict__ fb1,
                                            const float* __restrict__ fw2, const float* __restrict__ fb2) {
    __shared__ float Cs;
    if (threadIdx.x == 0) {
        // LN over size-1 axis -> exactly its bias term
        float y1 = ln1gb[1];
        float v  = y1 * aw[2] + ab[2];          // v constant; softmax uniform -> o = v
        float o  = v * aw[3] + ab[3];
        float y2 = ln2gb[1];
        float f  = fb2[0];
#pragma unroll
        for (int q = 0; q < 16; ++q) {
            float zz = y2 * fw1[q] + fb1[q];
            f += 0.5f * zz * (1.f + erff(zz * 0.70710678118654752f)) * fw2[q];
        }
        Cs = o + f;
    }
    __syncthreads();
    float C = Cs;
    int lane = threadIdx.x & 63;
    int row  = blockIdx.x * 4 + (threadIdx.x >> 6);
    float v1 = h1[(size_t)row * 64 + lane];
    float s1 = v1 * v1;
#pragma unroll
    for (int w = 1; w < 64; w <<= 1) s1 += __shfl_xor(s1, w, 64);
    float o1 = v1 / fmaxf(sqrtf(s1), 1e-12f);
    float v2 = v1 + C;
    float s2 = v2 * v2;
#pragma unroll
    for (int w = 1; w < 64; w <<= 1) s2 += __shfl_xor(s2, w, 64);
    float o2 = v2 / fmaxf(sqrtf(s2), 1e-12f);
    hf[(size_t)row * 128 + lane]      = o1;
    hf[(size_t)row * 128 + 64 + lane] = o2;
}

// ---------------- final GEMM: out = hf(16384x128) @ linW(128x349) + linb -----
__global__ __launch_bounds__(256) void k_gemm_out(const float* __restrict__ X,
                                                  const float* __restrict__ W,
                                                  const float* __restrict__ bias,
                                                  float* __restrict__ out) {
    __shared__ float Wl[128 * 64];
    __shared__ float Xl[64][33];
    const int tid = threadIdx.x;
    const int r0 = blockIdx.x * 64;
    const int c0 = blockIdx.y * 64;
    for (int idx = tid; idx < 128 * 64; idx += 256) {
        int k = idx >> 6, c = idx & 63;
        int gc = c0 + c;
        Wl[idx] = (gc < OUTD) ? W[(size_t)k * OUTD + gc] : 0.f;
    }
    float acc[16] = {0.f};
    const int rg = tid >> 2, h = tid & 3;
    for (int kc = 0; kc < 128; kc += 32) {
        __syncthreads();
        for (int idx = tid * 4; idx < 64 * 32; idx += 1024) {
            int row = idx >> 5, col = idx & 31;
            float4 v = *(const float4*)(X + (size_t)(r0 + row) * 128 + kc + col);
            Xl[row][col] = v.x; Xl[row][col + 1] = v.y;
            Xl[row][col + 2] = v.z; Xl[row][col + 3] = v.w;
        }
        __syncthreads();
        for (int kk = 0; kk < 32; ++kk) {
            float a = Xl[rg][kk];
            const float4* wr = (const float4*)(Wl + (kc + kk) * 64 + h * 16);
#pragma unroll
            for (int q = 0; q < 4; ++q) {
                float4 w = wr[q];
                acc[q * 4 + 0] += a * w.x; acc[q * 4 + 1] += a * w.y;
                acc[q * 4 + 2] += a * w.z; acc[q * 4 + 3] += a * w.w;
            }
        }
    }
    int n = r0 + rg;
#pragma unroll
    for (int q = 0; q < 16; ++q) {
        int c = c0 + h * 16 + q;
        if (c < OUTD) out[(size_t)n * OUTD + c] = acc[q] + bias[c];
    }
}

// ---------------- host ----------------
extern "C" void kernel_launch(void* const* d_in, const int* in_sizes, int n_in,
                              void* d_out, int out_size, void* d_ws, size_t ws_size,
                              hipStream_t stream) {
    const float* x_author = (const float*)d_in[0];
    const float* x_paper  = (const float*)d_in[1];
    const float* ntype    = (const float*)d_in[2];
    const float* W0  = (const float*)d_in[3];
    const float* al0 = (const float*)d_in[4];
    const float* ar0 = (const float*)d_in[5];
    const float* b0  = (const float*)d_in[6];
    const float* W1  = (const float*)d_in[7];
    const float* al1 = (const float*)d_in[8];
    const float* ar1 = (const float*)d_in[9];
    const float* b1  = (const float*)d_in[10];
    const float* ln1gb = (const float*)d_in[11];
    const float* attw  = (const float*)d_in[12];
    const float* attb  = (const float*)d_in[13];
    const float* ln2gb = (const float*)d_in[14];
    const float* fw1 = (const float*)d_in[15];
    const float* fb1 = (const float*)d_in[16];
    const float* fw2 = (const float*)d_in[17];
    const float* fb2 = (const float*)d_in[18];
    const float* linW = (const float*)d_in[19];
    const float* linb = (const float*)d_in[20];
    const int* srcW = (const int*)d_in[21];
    const int* dstW = (const int*)d_in[22];
    const int* srcC = (const int*)d_in[23];
    const int* dstC = (const int*)d_in[24];
    const int* srcR = (const int*)d_in[25];
    const int* dstR = (const int*)d_in[26];
    float* out = (float*)d_out;

    // ---- workspace carve-up ----
    float* ws = (float*)d_ws;
    size_t off = 0;
    float* ha  = ws + off; off += (size_t)N_A * IN_D;   // reused as hf at the end
    float* hp  = ws + off; off += (size_t)N_P * IN_D;
    float* fsW = ws + off; off += (size_t)N_A * HID;
    float* fsC = ws + off; off += (size_t)N_P * HID;
    float* fsR = ws + off; off += (size_t)N_P * HID;
    float* elw = ws + off; off += (size_t)N_A * NH;
    float* erw = ws + off; off += (size_t)N_P * NH;
    float* elc = ws + off; off += (size_t)N_P * NH;
    float* erc = ws + off; off += (size_t)N_P * NH;
    float* elr = ws + off; off += (size_t)N_P * NH;
    float* err = ws + off; off += (size_t)N_A * NH;
    float* oa0 = ws + off; off += (size_t)N_A * HID;
    float* op0 = ws + off; off += (size_t)N_P * HID;
    float* oa1 = ws + off; off += (size_t)N_A * HID;
    float* op1 = ws + off; off += (size_t)N_P * HID;
    int* cnt  = (int*)(ws + off); off += 3 * 16384;
    int* row  = (int*)(ws + off); off += 3 * 16385 + 1;   // +1 keeps alignment slack
    int* cur  = (int*)(ws + off); off += 3 * 16384;
    int* esW  = (int*)(ws + off); off += NE;
    int* esC  = (int*)(ws + off); off += NE;
    int* esR  = (int*)(ws + off); off += NE;
    float* hf = ha;   // ha/hp dead once layer-0 GEMM is done

    const int* rowW = row;
    const int* rowC = row + 16385;
    const int* rowR = row + 2 * 16385;

    // ---- layer job tables ----
    GemmJobs j0{};
    j0.X[0] = ha; j0.W[0] = W0;                    j0.F[0] = fsW; j0.EL[0] = elw; j0.ER[0] = nullptr;
    j0.AL[0] = al0;        j0.AR[0] = nullptr;
    j0.X[1] = hp; j0.W[1] = W0;                    j0.F[1] = nullptr; j0.EL[1] = nullptr; j0.ER[1] = erw;
    j0.AL[1] = nullptr;    j0.AR[1] = ar0;
    j0.X[2] = hp; j0.W[2] = W0 + IN_D * HID;       j0.F[2] = fsC; j0.EL[2] = elc; j0.ER[2] = erc;
    j0.AL[2] = al0 + 64;   j0.AR[2] = ar0 + 64;
    j0.X[3] = hp; j0.W[3] = W0 + 2 * IN_D * HID;   j0.F[3] = fsR; j0.EL[3] = elr; j0.ER[3] = nullptr;
    j0.AL[3] = al0 + 128;  j0.AR[3] = nullptr;
    j0.X[4] = ha; j0.W[4] = W0 + 2 * IN_D * HID;   j0.F[4] = nullptr; j0.EL[4] = nullptr; j0.ER[4] = err;
    j0.AL[4] = nullptr;    j0.AR[4] = ar0 + 128;

    GemmJobs j1{};
    j1.X[0] = oa0; j1.W[0] = W1;                   j1.F[0] = fsW; j1.EL[0] = elw; j1.ER[0] = nullptr;
    j1.AL[0] = al1;        j1.AR[0] = nullptr;
    j1.X[1] = op0; j1.W[1] = W1;                   j1.F[1] = nullptr; j1.EL[1] = nullptr; j1.ER[1] = erw;
    j1.AL[1] = nullptr;    j1.AR[1] = ar1;
    j1.X[2] = op0; j1.W[2] = W1 + HID * HID;       j1.F[2] = fsC; j1.EL[2] = elc; j1.ER[2] = erc;
    j1.AL[2] = al1 + 64;   j1.AR[2] = ar1 + 64;
    j1.X[3] = op0; j1.W[3] = W1 + 2 * HID * HID;   j1.F[3] = fsR; j1.EL[3] = elr; j1.ER[3] = nullptr;
    j1.AL[3] = al1 + 128;  j1.AR[3] = nullptr;
    j1.X[4] = oa0; j1.W[4] = W1 + 2 * HID * HID;   j1.F[4] = nullptr; j1.EL[4] = nullptr; j1.ER[4] = err;
    j1.AL[4] = nullptr;    j1.AR[4] = ar1 + 128;

    AggArgs a0{};
    a0.t[0] = {rowW, esW, elw, erw, fsW};
    a0.t[1] = {rowC, esC, elc, erc, fsC};
    a0.t[2] = {rowR, esR, elr, err, fsR};
    a0.b = b0; a0.op = op0; a0.oa = oa0;
    AggArgs a1 = a0;
    a1.b = b1; a1.op = op1; a1.oa = oa1;

    // ---- launches ----
    k_scale<<<(N_A * IN_D / 4 + 255) / 256, 256, 0, stream>>>(x_author, x_paper, ntype, ha, hp);

    // CSR build (edge lists constant across layers)
    k_zero<<<(3 * 16384 + 255) / 256, 256, 0, stream>>>(cnt);
    k_hist<<<3 * NE / 256, 256, 0, stream>>>(dstW, dstC, dstR, cnt);
    k_scan<<<3, 1024, 0, stream>>>(cnt, row, cur);
    k_scatter<<<3 * NE / 256, 256, 0, stream>>>(srcW, dstW, srcC, dstC, srcR, dstR, cur, esW, esC, esR);

    // layer 0
    k_gemm<IN_D, 0><<<dim3(N_A / 128, 1, 5), 256, 0, stream>>>(j0);
    k_agg<<<(N_P + N_A) / 4, 256, 0, stream>>>(a0);

    // layer 1 (relu folded into GEMM X loads)
    k_gemm<HID, 1><<<dim3(N_A / 128, 1, 5), 256, 0, stream>>>(j1);
    k_agg<<<(N_P + N_A) / 4, 256, 0, stream>>>(a1);

    // epilogue
    k_hf<<<N_P / 4, 256, 0, stream>>>(op1, hf, ln1gb, attw, attb, ln2gb, fw1, fb1, fw2, fb2);
    k_gemm_out<<<dim3(N_P / 64, (OUTD + 63) / 64), 256, 0, stream>>>(hf, linW, linb, out);
}

// Round 4
// 387.003 us; speedup vs baseline: 1.6463x; 1.6463x over previous
//
#include <hip/hip_runtime.h>
#include <math.h>

// ---------------- problem constants ----------------
constexpr int N_A   = 16384;
constexpr int N_P   = 16384;
constexpr int IN_D  = 128;
constexpr int HID   = 64;
constexpr int NH    = 4;    // heads
constexpr int OUTD  = 349;
constexpr int NE    = 262144; // edges per type (2^18)
constexpr float NEG = 0.2f;

__device__ __forceinline__ float lrelu(float x) { return x > 0.f ? x : NEG * x; }

// ---------------- kernel 1: ntype scaling ----------------
__global__ __launch_bounds__(256) void k_scale(const float* __restrict__ xa,
                                               const float* __restrict__ xp,
                                               const float* __restrict__ nt,
                                               float* __restrict__ ha,
                                               float* __restrict__ hp) {
    int i4 = blockIdx.x * 256 + threadIdx.x;           // one float4 each
    if (i4 >= N_A * IN_D / 4) return;
    int col4 = i4 & (IN_D / 4 - 1);
    float4 sa = ((const float4*)nt)[col4];
    float4 sp = ((const float4*)nt)[IN_D / 4 + col4];
    float4 a = ((const float4*)xa)[i4];
    a.x *= sa.x; a.y *= sa.y; a.z *= sa.z; a.w *= sa.w;
    ((float4*)ha)[i4] = a;
    float4 p = ((const float4*)xp)[i4];
    p.x *= sp.x; p.y *= sp.y; p.z *= sp.z; p.w *= sp.w;
    ((float4*)hp)[i4] = p;
}

// ---------------- CSR build (once per call; edge lists shared by both layers)
__global__ __launch_bounds__(256) void k_zero(int* __restrict__ cnt) {
    int i = blockIdx.x * 256 + threadIdx.x;
    if (i < 3 * 16384) cnt[i] = 0;
}

__global__ __launch_bounds__(256) void k_hist(const int* __restrict__ dW, const int* __restrict__ dC,
                                              const int* __restrict__ dR, int* __restrict__ cnt) {
    int idx = blockIdx.x * 256 + threadIdx.x;   // 3*NE
    int t = idx >> 18, i = idx & (NE - 1);
    const int* d = t == 0 ? dW : t == 1 ? dC : dR;
    atomicAdd(cnt + t * 16384 + d[i], 1);
}

__global__ __launch_bounds__(1024) void k_scan(const int* __restrict__ cnt, int* __restrict__ row,
                                               int* __restrict__ cur) {
    int b = blockIdx.x;                          // type
    const int* c = cnt + b * 16384;
    int* r = row + b * 16385;
    int* q = cur + b * 16384;
    __shared__ int part[1024];
    int t = threadIdx.x;
    int loc[16], s = 0;
#pragma unroll
    for (int i = 0; i < 16; ++i) { loc[i] = s; s += c[t * 16 + i]; }
    part[t] = s;
    __syncthreads();
    for (int w = 1; w < 1024; w <<= 1) {
        int v = (t >= w) ? part[t - w] : 0;
        __syncthreads();
        part[t] += v;
        __syncthreads();
    }
    int off = (t > 0) ? part[t - 1] : 0;
#pragma unroll
    for (int i = 0; i < 16; ++i) {
        int v = off + loc[i];
        r[t * 16 + i] = v;
        q[t * 16 + i] = v;
    }
    if (t == 1023) r[16384] = part[1023];
}

__global__ __launch_bounds__(256) void k_scatter(const int* __restrict__ sW, const int* __restrict__ dW,
                                                 const int* __restrict__ sC, const int* __restrict__ dC,
                                                 const int* __restrict__ sR, const int* __restrict__ dR,
                                                 int* __restrict__ cur,
                                                 int* __restrict__ eW, int* __restrict__ eC,
                                                 int* __restrict__ eR) {
    int idx = blockIdx.x * 256 + threadIdx.x;   // 3*NE
    int t = idx >> 18, i = idx & (NE - 1);
    const int* sp = t == 0 ? sW : t == 1 ? sC : sR;
    const int* dp = t == 0 ? dW : t == 1 ? dC : dR;
    int* ep = t == 0 ? eW : t == 1 ? eC : eR;
    int pos = atomicAdd(cur + t * 16384 + dp[i], 1);
    ep[pos] = sp[i];
}

// ---------------- batched GEMM (X@W) + el/er head reductions -------
// Shape cloned from k_gemm_out (proven non-spilling): 64 rows/block, one row
// per 4-thread group, acc[16]/thread. The 128-row/acc[2][16] variant spilled
// (VGPR=256, occ 9.7%, 400 MB scratch WRITE — measured rounds 2-3).
struct GemmJobs {
    const float* X[5];  const float* W[5];
    float* F[5];        float* EL[5];       float* ER[5];
    const float* AL[5]; const float* AR[5];
};

template <int K, int RELU>
__global__ __launch_bounds__(256) void k_gemm(GemmJobs j) {
    __shared__ float Wl[K * 64];
    __shared__ float Xl[64][33];

    const float* __restrict__ X;  const float* __restrict__ Wp;
    float* __restrict__ F;  float* __restrict__ EL;  float* __restrict__ ER;
    const float* __restrict__ AL; const float* __restrict__ AR;
    switch (blockIdx.z) {                         // block-uniform, static indices
      case 0: X=j.X[0]; Wp=j.W[0]; F=j.F[0]; EL=j.EL[0]; ER=j.ER[0]; AL=j.AL[0]; AR=j.AR[0]; break;
      case 1: X=j.X[1]; Wp=j.W[1]; F=j.F[1]; EL=j.EL[1]; ER=j.ER[1]; AL=j.AL[1]; AR=j.AR[1]; break;
      case 2: X=j.X[2]; Wp=j.W[2]; F=j.F[2]; EL=j.EL[2]; ER=j.ER[2]; AL=j.AL[2]; AR=j.AR[2]; break;
      case 3: X=j.X[3]; Wp=j.W[3]; F=j.F[3]; EL=j.EL[3]; ER=j.ER[3]; AL=j.AL[3]; AR=j.AR[3]; break;
      default: X=j.X[4]; Wp=j.W[4]; F=j.F[4]; EL=j.EL[4]; ER=j.ER[4]; AL=j.AL[4]; AR=j.AR[4]; break;
    }

    const int tid = threadIdx.x;
    const int r0 = blockIdx.x * 64;

    for (int idx = tid * 4; idx < K * 64; idx += 1024)
        *(float4*)(Wl + idx) = *(const float4*)(Wp + idx);

    const int rg = tid >> 2;      // 0..63 -> row
    const int h  = tid & 3;       // head / 16-col group
    float acc[16] = {0.f};

    for (int kc = 0; kc < K; kc += 32) {
        __syncthreads();
        for (int idx = tid * 4; idx < 64 * 32; idx += 1024) {
            int row = idx >> 5, col = idx & 31;
            float4 v = *(const float4*)(X + (size_t)(r0 + row) * K + kc + col);
            if (RELU) {
                v.x = fmaxf(v.x, 0.f); v.y = fmaxf(v.y, 0.f);
                v.z = fmaxf(v.z, 0.f); v.w = fmaxf(v.w, 0.f);
            }
            Xl[row][col] = v.x; Xl[row][col + 1] = v.y;
            Xl[row][col + 2] = v.z; Xl[row][col + 3] = v.w;
        }
        __syncthreads();
        for (int kk = 0; kk < 32; ++kk) {
            float a = Xl[rg][kk];
            const float4* wr = (const float4*)(Wl + (kc + kk) * 64 + h * 16);
#pragma unroll
            for (int q = 0; q < 4; ++q) {
                float4 w = wr[q];
                acc[q * 4 + 0] += a * w.x; acc[q * 4 + 1] += a * w.y;
                acc[q * 4 + 2] += a * w.z; acc[q * 4 + 3] += a * w.w;
            }
        }
    }

    size_t n = (size_t)r0 + rg;
    if (F) {
        float4* dst = (float4*)(F + n * 64 + h * 16);
        dst[0] = make_float4(acc[0],  acc[1],  acc[2],  acc[3]);
        dst[1] = make_float4(acc[4],  acc[5],  acc[6],  acc[7]);
        dst[2] = make_float4(acc[8],  acc[9],  acc[10], acc[11]);
        dst[3] = make_float4(acc[12], acc[13], acc[14], acc[15]);
    }
    if (EL) {
        const float* al = AL + h * 16;
        float s = 0.f;
#pragma unroll
        for (int q = 0; q < 16; ++q) s += acc[q] * al[q];
        EL[n * 4 + h] = s;
    }
    if (ER) {
        const float* ar = AR + h * 16;
        float s = 0.f;
#pragma unroll
        for (int q = 0; q < 16; ++q) s += acc[q] * ar[q];
        ER[n * 4 + h] = s;
    }
}

// ---------------- per-destination gather aggregation (no atomics) ----------
struct AggType { const int* row; const int* es; const float* el; const float* er; const float* fs; };
struct AggArgs { AggType t[3]; const float* b; float* op; float* oa; };

__device__ __forceinline__ float agg_one(const int* __restrict__ rowv, const int* __restrict__ es,
                                         const float* __restrict__ el, const float* __restrict__ er,
                                         const float* __restrict__ fs, int d, int lane, int h) {
    int start = rowv[d], end = rowv[d + 1];
    if (end <= start) return 0.f;
    float4 r4 = *(const float4*)(er + (size_t)d * 4);
    // ---- phase A: per-head max over incident edges (lane-strided) ----
    float4 m4 = make_float4(-INFINITY, -INFINITY, -INFINITY, -INFINITY);
    for (int e = start + lane; e < end; e += 64) {
        int sn = es[e];
        float4 l4 = *(const float4*)(el + (size_t)sn * 4);
        m4.x = fmaxf(m4.x, lrelu(l4.x + r4.x));
        m4.y = fmaxf(m4.y, lrelu(l4.y + r4.y));
        m4.z = fmaxf(m4.z, lrelu(l4.z + r4.z));
        m4.w = fmaxf(m4.w, lrelu(l4.w + r4.w));
    }
#pragma unroll
    for (int w = 1; w < 64; w <<= 1) {
        m4.x = fmaxf(m4.x, __shfl_xor(m4.x, w, 64));
        m4.y = fmaxf(m4.y, __shfl_xor(m4.y, w, 64));
        m4.z = fmaxf(m4.z, __shfl_xor(m4.z, w, 64));
        m4.w = fmaxf(m4.w, __shfl_xor(m4.w, w, 64));
    }
    // ---- phase A2: denominator ----
    float4 s4 = make_float4(0.f, 0.f, 0.f, 0.f);
    for (int e = start + lane; e < end; e += 64) {
        int sn = es[e];
        float4 l4 = *(const float4*)(el + (size_t)sn * 4);
        s4.x += __expf(lrelu(l4.x + r4.x) - m4.x);
        s4.y += __expf(lrelu(l4.y + r4.y) - m4.y);
        s4.z += __expf(lrelu(l4.z + r4.z) - m4.z);
        s4.w += __expf(lrelu(l4.w + r4.w) - m4.w);
    }
#pragma unroll
    for (int w = 1; w < 64; w <<= 1) {
        s4.x += __shfl_xor(s4.x, w, 64);
        s4.y += __shfl_xor(s4.y, w, 64);
        s4.z += __shfl_xor(s4.z, w, 64);
        s4.w += __shfl_xor(s4.w, w, 64);
    }
    float mh = h == 0 ? m4.x : h == 1 ? m4.y : h == 2 ? m4.z : m4.w;
    float dh = h == 0 ? s4.x : h == 1 ? s4.y : h == 2 ? s4.z : s4.w;
    float rh = h == 0 ? r4.x : h == 1 ? r4.y : h == 2 ? r4.z : r4.w;
    float inv = 1.f / fmaxf(dh, 1e-9f);
    // ---- phase B: weighted feature accumulation; lane owns one column ----
    float acc = 0.f;
    for (int e = start; e < end; ++e) {
        int sn = es[e];                             // uniform across wave
        float a = __expf(lrelu(el[(size_t)sn * 4 + h] + rh) - mh) * inv;
        acc = fmaf(a, fs[(size_t)sn * 64 + lane], acc);
    }
    return acc;
}

__global__ __launch_bounds__(256) void k_agg(AggArgs A) {
    int wid = (blockIdx.x * 256 + threadIdx.x) >> 6;  // one wave per dst node
    int lane = threadIdx.x & 63;
    int h = lane >> 4;
    if (wid < N_P) {
        // paper node: writes-GAT + cites-GAT (+ both biases)
        float acc = A.b[lane] + A.b[64 + lane];
        acc += agg_one(A.t[0].row, A.t[0].es, A.t[0].el, A.t[0].er, A.t[0].fs, wid, lane, h);
        acc += agg_one(A.t[1].row, A.t[1].es, A.t[1].el, A.t[1].er, A.t[1].fs, wid, lane, h);
        A.op[(size_t)wid * 64 + lane] = acc;
    } else {
        int d = wid - N_P;
        float acc = A.b[128 + lane];
        acc += agg_one(A.t[2].row, A.t[2].es, A.t[2].el, A.t[2].er, A.t[2].fs, d, lane, h);
        A.oa[(size_t)d * 64 + lane] = acc;
    }
}

// ---------------- hf build: h2 = h1 + C, row l2-normalize, concat ------------
__global__ __launch_bounds__(256) void k_hf(const float* __restrict__ h1, float* __restrict__ hf,
                                            const float* __restrict__ ln1gb,
                                            const float* __restrict__ aw, const float* __restrict__ ab,
                                            const float* __restrict__ ln2gb,
                                            const float* __restrict__ fw1, const float* __restrict__ fb1,
                                            const float* __restrict__ fw2, const float* __restrict__ fb2) {
    __shared__ float Cs;
    if (threadIdx.x == 0) {
        // LN over size-1 axis -> exactly its bias term
        float y1 = ln1gb[1];
        float v  = y1 * aw[2] + ab[2];          // v constant; softmax uniform -> o = v
        float o  = v * aw[3] + ab[3];
        float y2 = ln2gb[1];
        float f  = fb2[0];
#pragma unroll
        for (int q = 0; q < 16; ++q) {
            float zz = y2 * fw1[q] + fb1[q];
            f += 0.5f * zz * (1.f + erff(zz * 0.70710678118654752f)) * fw2[q];
        }
        Cs = o + f;
    }
    __syncthreads();
    float C = Cs;
    int lane = threadIdx.x & 63;
    int row  = blockIdx.x * 4 + (threadIdx.x >> 6);
    float v1 = h1[(size_t)row * 64 + lane];
    float s1 = v1 * v1;
#pragma unroll
    for (int w = 1; w < 64; w <<= 1) s1 += __shfl_xor(s1, w, 64);
    float o1 = v1 / fmaxf(sqrtf(s1), 1e-12f);
    float v2 = v1 + C;
    float s2 = v2 * v2;
#pragma unroll
    for (int w = 1; w < 64; w <<= 1) s2 += __shfl_xor(s2, w, 64);
    float o2 = v2 / fmaxf(sqrtf(s2), 1e-12f);
    hf[(size_t)row * 128 + lane]      = o1;
    hf[(size_t)row * 128 + 64 + lane] = o2;
}

// ---------------- final GEMM: out = hf(16384x128) @ linW(128x349) + linb -----
__global__ __launch_bounds__(256) void k_gemm_out(const float* __restrict__ X,
                                                  const float* __restrict__ W,
                                                  const float* __restrict__ bias,
                                                  float* __restrict__ out) {
    __shared__ float Wl[128 * 64];
    __shared__ float Xl[64][33];
    const int tid = threadIdx.x;
    const int r0 = blockIdx.x * 64;
    const int c0 = blockIdx.y * 64;
    for (int idx = tid; idx < 128 * 64; idx += 256) {
        int k = idx >> 6, c = idx & 63;
        int gc = c0 + c;
        Wl[idx] = (gc < OUTD) ? W[(size_t)k * OUTD + gc] : 0.f;
    }
    float acc[16] = {0.f};
    const int rg = tid >> 2, h = tid & 3;
    for (int kc = 0; kc < 128; kc += 32) {
        __syncthreads();
        for (int idx = tid * 4; idx < 64 * 32; idx += 1024) {
            int row = idx >> 5, col = idx & 31;
            float4 v = *(const float4*)(X + (size_t)(r0 + row) * 128 + kc + col);
            Xl[row][col] = v.x; Xl[row][col + 1] = v.y;
            Xl[row][col + 2] = v.z; Xl[row][col + 3] = v.w;
        }
        __syncthreads();
        for (int kk = 0; kk < 32; ++kk) {
            float a = Xl[rg][kk];
            const float4* wr = (const float4*)(Wl + (kc + kk) * 64 + h * 16);
#pragma unroll
            for (int q = 0; q < 4; ++q) {
                float4 w = wr[q];
                acc[q * 4 + 0] += a * w.x; acc[q * 4 + 1] += a * w.y;
                acc[q * 4 + 2] += a * w.z; acc[q * 4 + 3] += a * w.w;
            }
        }
    }
    int n = r0 + rg;
#pragma unroll
    for (int q = 0; q < 16; ++q) {
        int c = c0 + h * 16 + q;
        if (c < OUTD) out[(size_t)n * OUTD + c] = acc[q] + bias[c];
    }
}

// ---------------- host ----------------
extern "C" void kernel_launch(void* const* d_in, const int* in_sizes, int n_in,
                              void* d_out, int out_size, void* d_ws, size_t ws_size,
                              hipStream_t stream) {
    const float* x_author = (const float*)d_in[0];
    const float* x_paper  = (const float*)d_in[1];
    const float* ntype    = (const float*)d_in[2];
    const float* W0  = (const float*)d_in[3];
    const float* al0 = (const float*)d_in[4];
    const float* ar0 = (const float*)d_in[5];
    const float* b0  = (const float*)d_in[6];
    const float* W1  = (const float*)d_in[7];
    const float* al1 = (const float*)d_in[8];
    const float* ar1 = (const float*)d_in[9];
    const float* b1  = (const float*)d_in[10];
    const float* ln1gb = (const float*)d_in[11];
    const float* attw  = (const float*)d_in[12];
    const float* attb  = (const float*)d_in[13];
    const float* ln2gb = (const float*)d_in[14];
    const float* fw1 = (const float*)d_in[15];
    const float* fb1 = (const float*)d_in[16];
    const float* fw2 = (const float*)d_in[17];
    const float* fb2 = (const float*)d_in[18];
    const float* linW = (const float*)d_in[19];
    const float* linb = (const float*)d_in[20];
    const int* srcW = (const int*)d_in[21];
    const int* dstW = (const int*)d_in[22];
    const int* srcC = (const int*)d_in[23];
    const int* dstC = (const int*)d_in[24];
    const int* srcR = (const int*)d_in[25];
    const int* dstR = (const int*)d_in[26];
    float* out = (float*)d_out;

    // ---- workspace carve-up ----
    float* ws = (float*)d_ws;
    size_t off = 0;
    float* ha  = ws + off; off += (size_t)N_A * IN_D;   // reused as hf at the end
    float* hp  = ws + off; off += (size_t)N_P * IN_D;
    float* fsW = ws + off; off += (size_t)N_A * HID;
    float* fsC = ws + off; off += (size_t)N_P * HID;
    float* fsR = ws + off; off += (size_t)N_P * HID;
    float* elw = ws + off; off += (size_t)N_A * NH;
    float* erw = ws + off; off += (size_t)N_P * NH;
    float* elc = ws + off; off += (size_t)N_P * NH;
    float* erc = ws + off; off += (size_t)N_P * NH;
    float* elr = ws + off; off += (size_t)N_P * NH;
    float* err = ws + off; off += (size_t)N_A * NH;
    float* oa0 = ws + off; off += (size_t)N_A * HID;
    float* op0 = ws + off; off += (size_t)N_P * HID;
    float* oa1 = ws + off; off += (size_t)N_A * HID;
    float* op1 = ws + off; off += (size_t)N_P * HID;
    int* cnt  = (int*)(ws + off); off += 3 * 16384;
    int* row  = (int*)(ws + off); off += 3 * 16385 + 1;   // +1 keeps alignment slack
    int* cur  = (int*)(ws + off); off += 3 * 16384;
    int* esW  = (int*)(ws + off); off += NE;
    int* esC  = (int*)(ws + off); off += NE;
    int* esR  = (int*)(ws + off); off += NE;
    float* hf = ha;   // ha/hp dead once layer-0 GEMM is done

    const int* rowW = row;
    const int* rowC = row + 16385;
    const int* rowR = row + 2 * 16385;

    // ---- layer job tables ----
    GemmJobs j0{};
    j0.X[0] = ha; j0.W[0] = W0;                    j0.F[0] = fsW; j0.EL[0] = elw; j0.ER[0] = nullptr;
    j0.AL[0] = al0;        j0.AR[0] = nullptr;
    j0.X[1] = hp; j0.W[1] = W0;                    j0.F[1] = nullptr; j0.EL[1] = nullptr; j0.ER[1] = erw;
    j0.AL[1] = nullptr;    j0.AR[1] = ar0;
    j0.X[2] = hp; j0.W[2] = W0 + IN_D * HID;       j0.F[2] = fsC; j0.EL[2] = elc; j0.ER[2] = erc;
    j0.AL[2] = al0 + 64;   j0.AR[2] = ar0 + 64;
    j0.X[3] = hp; j0.W[3] = W0 + 2 * IN_D * HID;   j0.F[3] = fsR; j0.EL[3] = elr; j0.ER[3] = nullptr;
    j0.AL[3] = al0 + 128;  j0.AR[3] = nullptr;
    j0.X[4] = ha; j0.W[4] = W0 + 2 * IN_D * HID;   j0.F[4] = nullptr; j0.EL[4] = nullptr; j0.ER[4] = err;
    j0.AL[4] = nullptr;    j0.AR[4] = ar0 + 128;

    GemmJobs j1{};
    j1.X[0] = oa0; j1.W[0] = W1;                   j1.F[0] = fsW; j1.EL[0] = elw; j1.ER[0] = nullptr;
    j1.AL[0] = al1;        j1.AR[0] = nullptr;
    j1.X[1] = op0; j1.W[1] = W1;                   j1.F[1] = nullptr; j1.EL[1] = nullptr; j1.ER[1] = erw;
    j1.AL[1] = nullptr;    j1.AR[1] = ar1;
    j1.X[2] = op0; j1.W[2] = W1 + HID * HID;       j1.F[2] = fsC; j1.EL[2] = elc; j1.ER[2] = erc;
    j1.AL[2] = al1 + 64;   j1.AR[2] = ar1 + 64;
    j1.X[3] = op0; j1.W[3] = W1 + 2 * HID * HID;   j1.F[3] = fsR; j1.EL[3] = elr; j1.ER[3] = nullptr;
    j1.AL[3] = al1 + 128;  j1.AR[3] = nullptr;
    j1.X[4] = oa0; j1.W[4] = W1 + 2 * HID * HID;   j1.F[4] = nullptr; j1.EL[4] = nullptr; j1.ER[4] = err;
    j1.AL[4] = nullptr;    j1.AR[4] = ar1 + 128;

    AggArgs a0{};
    a0.t[0] = {rowW, esW, elw, erw, fsW};
    a0.t[1] = {rowC, esC, elc, erc, fsC};
    a0.t[2] = {rowR, esR, elr, err, fsR};
    a0.b = b0; a0.op = op0; a0.oa = oa0;
    AggArgs a1 = a0;
    a1.b = b1; a1.op = op1; a1.oa = oa1;

    // ---- launches ----
    k_scale<<<(N_A * IN_D / 4 + 255) / 256, 256, 0, stream>>>(x_author, x_paper, ntype, ha, hp);

    // CSR build (edge lists constant across layers)
    k_zero<<<(3 * 16384 + 255) / 256, 256, 0, stream>>>(cnt);
    k_hist<<<3 * NE / 256, 256, 0, stream>>>(dstW, dstC, dstR, cnt);
    k_scan<<<3, 1024, 0, stream>>>(cnt, row, cur);
    k_scatter<<<3 * NE / 256, 256, 0, stream>>>(srcW, dstW, srcC, dstC, srcR, dstR, cur, esW, esC, esR);

    // layer 0
    k_gemm<IN_D, 0><<<dim3(N_A / 64, 1, 5), 256, 0, stream>>>(j0);
    k_agg<<<(N_P + N_A) / 4, 256, 0, stream>>>(a0);

    // layer 1 (relu folded into GEMM X loads)
    k_gemm<HID, 1><<<dim3(N_A / 64, 1, 5), 256, 0, stream>>>(j1);
    k_agg<<<(N_P + N_A) / 4, 256, 0, stream>>>(a1);

    // epilogue
    k_hf<<<N_P / 4, 256, 0, stream>>>(op1, hf, ln1gb, attw, attb, ln2gb, fw1, fb1, fw2, fb2);
    k_gemm_out<<<dim3(N_P / 64, (OUTD + 63) / 64), 256, 0, stream>>>(hf, linW, linb, out);
}

// Round 5
// 297.241 us; speedup vs baseline: 2.1435x; 1.3020x over previous
//
#include <hip/hip_runtime.h>
#include <math.h>

// ---------------- problem constants ----------------
constexpr int N_A   = 16384;
constexpr int N_P   = 16384;
constexpr int IN_D  = 128;
constexpr int HID   = 64;
constexpr int NH    = 4;    // heads
constexpr int OUTD  = 349;
constexpr int NE    = 262144; // edges per type (2^18)
constexpr float NEG = 0.2f;

__device__ __forceinline__ float lrelu(float x) { return x > 0.f ? x : NEG * x; }

// ---------------- CSR build (once per call; edge lists shared by both layers)
__global__ __launch_bounds__(256) void k_zero(int* __restrict__ cnt) {
    int i = blockIdx.x * 256 + threadIdx.x;
    if (i < 3 * 16384) cnt[i] = 0;
}

__global__ __launch_bounds__(256) void k_hist(const int* __restrict__ dW, const int* __restrict__ dC,
                                              const int* __restrict__ dR, int* __restrict__ cnt) {
    int idx = blockIdx.x * 256 + threadIdx.x;   // 3*NE
    int t = idx >> 18, i = idx & (NE - 1);
    const int* d = t == 0 ? dW : t == 1 ? dC : dR;
    atomicAdd(cnt + t * 16384 + d[i], 1);
}

__global__ __launch_bounds__(1024) void k_scan(const int* __restrict__ cnt, int* __restrict__ row,
                                               int* __restrict__ cur) {
    int b = blockIdx.x;                          // type
    const int* c = cnt + b * 16384;
    int* r = row + b * 16385;
    int* q = cur + b * 16384;
    __shared__ int part[1024];
    int t = threadIdx.x;
    int loc[16], s = 0;
#pragma unroll
    for (int i = 0; i < 16; ++i) { loc[i] = s; s += c[t * 16 + i]; }
    part[t] = s;
    __syncthreads();
    for (int w = 1; w < 1024; w <<= 1) {
        int v = (t >= w) ? part[t - w] : 0;
        __syncthreads();
        part[t] += v;
        __syncthreads();
    }
    int off = (t > 0) ? part[t - 1] : 0;
#pragma unroll
    for (int i = 0; i < 16; ++i) {
        int v = off + loc[i];
        r[t * 16 + i] = v;
        q[t * 16 + i] = v;
    }
    if (t == 1023) r[16384] = part[1023];
}

__global__ __launch_bounds__(256) void k_scatter(const int* __restrict__ sW, const int* __restrict__ dW,
                                                 const int* __restrict__ sC, const int* __restrict__ dC,
                                                 const int* __restrict__ sR, const int* __restrict__ dR,
                                                 int* __restrict__ cur,
                                                 int* __restrict__ eW, int* __restrict__ eC,
                                                 int* __restrict__ eR) {
    int idx = blockIdx.x * 256 + threadIdx.x;   // 3*NE
    int t = idx >> 18, i = idx & (NE - 1);
    const int* sp = t == 0 ? sW : t == 1 ? sC : sR;
    const int* dp = t == 0 ? dW : t == 1 ? dC : dR;
    int* ep = t == 0 ? eW : t == 1 ? eC : eR;
    int pos = atomicAdd(cur + t * 16384 + dp[i], 1);
    ep[pos] = sp[i];
}

// ---------------- batched GEMM (X@W) + el/er head reductions -------
// 64 rows/block, one row per 4-thread group, acc[16]/thread (proven
// non-spilling shape; 128-row/acc[2][16] spilled: VGPR=256, occ 9.7%).
// NT != nullptr folds the ntype column-scale into the X load (layer 0).
struct GemmJobs {
    const float* X[5];  const float* W[5];  const float* NT[5];
    float* F[5];        float* EL[5];       float* ER[5];
    const float* AL[5]; const float* AR[5];
};

template <int K, int RELU>
__global__ __launch_bounds__(256) void k_gemm(GemmJobs j) {
    __shared__ float Wl[K * 64];
    __shared__ float Xl[64][33];

    const float* __restrict__ X;  const float* __restrict__ Wp;  const float* __restrict__ NTp;
    float* __restrict__ F;  float* __restrict__ EL;  float* __restrict__ ER;
    const float* __restrict__ AL; const float* __restrict__ AR;
    switch (blockIdx.z) {                         // block-uniform, static indices
      case 0: X=j.X[0]; Wp=j.W[0]; NTp=j.NT[0]; F=j.F[0]; EL=j.EL[0]; ER=j.ER[0]; AL=j.AL[0]; AR=j.AR[0]; break;
      case 1: X=j.X[1]; Wp=j.W[1]; NTp=j.NT[1]; F=j.F[1]; EL=j.EL[1]; ER=j.ER[1]; AL=j.AL[1]; AR=j.AR[1]; break;
      case 2: X=j.X[2]; Wp=j.W[2]; NTp=j.NT[2]; F=j.F[2]; EL=j.EL[2]; ER=j.ER[2]; AL=j.AL[2]; AR=j.AR[2]; break;
      case 3: X=j.X[3]; Wp=j.W[3]; NTp=j.NT[3]; F=j.F[3]; EL=j.EL[3]; ER=j.ER[3]; AL=j.AL[3]; AR=j.AR[3]; break;
      default: X=j.X[4]; Wp=j.W[4]; NTp=j.NT[4]; F=j.F[4]; EL=j.EL[4]; ER=j.ER[4]; AL=j.AL[4]; AR=j.AR[4]; break;
    }

    const int tid = threadIdx.x;
    const int r0 = blockIdx.x * 64;

    for (int idx = tid * 4; idx < K * 64; idx += 1024)
        *(float4*)(Wl + idx) = *(const float4*)(Wp + idx);

    const int rg = tid >> 2;      // 0..63 -> row
    const int h  = tid & 3;       // head / 16-col group
    float acc[16] = {0.f};

    for (int kc = 0; kc < K; kc += 32) {
        __syncthreads();
        for (int idx = tid * 4; idx < 64 * 32; idx += 1024) {
            int row = idx >> 5, col = idx & 31;
            float4 v = *(const float4*)(X + (size_t)(r0 + row) * K + kc + col);
            if (RELU) {
                v.x = fmaxf(v.x, 0.f); v.y = fmaxf(v.y, 0.f);
                v.z = fmaxf(v.z, 0.f); v.w = fmaxf(v.w, 0.f);
            }
            if (NTp) {
                float4 s = *(const float4*)(NTp + kc + col);
                v.x *= s.x; v.y *= s.y; v.z *= s.z; v.w *= s.w;
            }
            Xl[row][col] = v.x; Xl[row][col + 1] = v.y;
            Xl[row][col + 2] = v.z; Xl[row][col + 3] = v.w;
        }
        __syncthreads();
        for (int kk = 0; kk < 32; ++kk) {
            float a = Xl[rg][kk];
            const float4* wr = (const float4*)(Wl + (kc + kk) * 64 + h * 16);
#pragma unroll
            for (int q = 0; q < 4; ++q) {
                float4 w = wr[q];
                acc[q * 4 + 0] += a * w.x; acc[q * 4 + 1] += a * w.y;
                acc[q * 4 + 2] += a * w.z; acc[q * 4 + 3] += a * w.w;
            }
        }
    }

    size_t n = (size_t)r0 + rg;
    if (F) {
        float4* dst = (float4*)(F + n * 64 + h * 16);
        dst[0] = make_float4(acc[0],  acc[1],  acc[2],  acc[3]);
        dst[1] = make_float4(acc[4],  acc[5],  acc[6],  acc[7]);
        dst[2] = make_float4(acc[8],  acc[9],  acc[10], acc[11]);
        dst[3] = make_float4(acc[12], acc[13], acc[14], acc[15]);
    }
    if (EL) {
        const float* al = AL + h * 16;
        float s = 0.f;
#pragma unroll
        for (int q = 0; q < 16; ++q) s += acc[q] * al[q];
        EL[n * 4 + h] = s;
    }
    if (ER) {
        const float* ar = AR + h * 16;
        float s = 0.f;
#pragma unroll
        for (int q = 0; q < 16; ++q) s += acc[q] * ar[q];
        ER[n * 4 + h] = s;
    }
}

// ---------------- per-destination gather aggregation (no atomics) ----------
// 16-edge chunks: lane l owns (edge l&15, head l>>4). One exp per lane per
// chunk; sn broadcast via readlane (uniform j), head weight via one bpermute.
// Normalization deferred: acc = sum(w * fs) then * 1/den.
struct AggType { const int* row; const int* es; const float* el; const float* er; const float* fs; };
struct AggArgs { AggType t[3]; const float* b; float* op; float* oa; };

__device__ __forceinline__ float agg16(const int* __restrict__ rowv, const int* __restrict__ es,
                                       const float* __restrict__ el, const float* __restrict__ er,
                                       const float* __restrict__ fs, int d, int lane) {
    int start = rowv[d], end = rowv[d + 1];
    int deg = end - start;
    if (deg <= 0) return 0.f;
    const int g = lane >> 4, j16 = lane & 15;
    const float rh = er[(size_t)d * 4 + g];
    const int nch = (deg + 15) >> 4;

    // pass 1: per-(edge,head) score max (within 16-lane group = per head)
    float m = -INFINITY;
    for (int c = 0; c < nch; ++c) {
        int o = c * 16 + j16;
        int sn = es[start + (o < deg ? o : 0)];
        float ev = lrelu(el[(size_t)sn * 4 + g] + rh);
        if (o < deg) m = fmaxf(m, ev);
    }
#pragma unroll
    for (int w = 1; w < 16; w <<= 1) m = fmaxf(m, __shfl_xor(m, w, 64));

    // pass 2: weights, denominator partials, unnormalized accumulation
    float den = 0.f, acc = 0.f;
    for (int c = 0; c < nch; ++c) {
        int o = c * 16 + j16;
        int sn = es[start + (o < deg ? o : 0)];
        float ev = (o < deg) ? lrelu(el[(size_t)sn * 4 + g] + rh) : -INFINITY;
        float wv = __expf(ev - m);          // 0 for padding slots
        den += wv;
#pragma unroll
        for (int jj = 0; jj < 16; ++jj) {
            int snj = __shfl(sn, jj, 64);                    // v_readlane (uniform)
            float wj = __shfl(wv, (lane & 48) + jj, 64);     // head-specific weight
            acc = fmaf(wj, fs[(size_t)snj * 64 + lane], acc);
        }
    }
#pragma unroll
    for (int w = 1; w < 16; w <<= 1) den += __shfl_xor(den, w, 64);
    return acc * (1.f / fmaxf(den, 1e-9f));
}

__global__ __launch_bounds__(256) void k_agg(AggArgs A) {
    int wid = (blockIdx.x * 256 + threadIdx.x) >> 6;  // one wave per dst node
    int lane = threadIdx.x & 63;
    if (wid < N_P) {
        // paper node: writes-GAT + cites-GAT (+ both biases)
        float acc = A.b[lane] + A.b[64 + lane];
        acc += agg16(A.t[0].row, A.t[0].es, A.t[0].el, A.t[0].er, A.t[0].fs, wid, lane);
        acc += agg16(A.t[1].row, A.t[1].es, A.t[1].el, A.t[1].er, A.t[1].fs, wid, lane);
        A.op[(size_t)wid * 64 + lane] = acc;
    } else {
        int d = wid - N_P;
        float acc = A.b[128 + lane];
        acc += agg16(A.t[2].row, A.t[2].es, A.t[2].el, A.t[2].er, A.t[2].fs, d, lane);
        A.oa[(size_t)d * 64 + lane] = acc;
    }
}

// ---------------- hf build: h2 = h1 + C, row l2-normalize, concat ------------
__global__ __launch_bounds__(256) void k_hf(const float* __restrict__ h1, float* __restrict__ hf,
                                            const float* __restrict__ ln1gb,
                                            const float* __restrict__ aw, const float* __restrict__ ab,
                                            const float* __restrict__ ln2gb,
                                            const float* __restrict__ fw1, const float* __restrict__ fb1,
                                            const float* __restrict__ fw2, const float* __restrict__ fb2) {
    __shared__ float Cs;
    if (threadIdx.x == 0) {
        // LN over size-1 axis -> exactly its bias term
        float y1 = ln1gb[1];
        float v  = y1 * aw[2] + ab[2];          // v constant; softmax uniform -> o = v
        float o  = v * aw[3] + ab[3];
        float y2 = ln2gb[1];
        float f  = fb2[0];
#pragma unroll
        for (int q = 0; q < 16; ++q) {
            float zz = y2 * fw1[q] + fb1[q];
            f += 0.5f * zz * (1.f + erff(zz * 0.70710678118654752f)) * fw2[q];
        }
        Cs = o + f;
    }
    __syncthreads();
    float C = Cs;
    int lane = threadIdx.x & 63;
    int row  = blockIdx.x * 4 + (threadIdx.x >> 6);
    float v1 = h1[(size_t)row * 64 + lane];
    float s1 = v1 * v1;
#pragma unroll
    for (int w = 1; w < 64; w <<= 1) s1 += __shfl_xor(s1, w, 64);
    float o1 = v1 / fmaxf(sqrtf(s1), 1e-12f);
    float v2 = v1 + C;
    float s2 = v2 * v2;
#pragma unroll
    for (int w = 1; w < 64; w <<= 1) s2 += __shfl_xor(s2, w, 64);
    float o2 = v2 / fmaxf(sqrtf(s2), 1e-12f);
    hf[(size_t)row * 128 + lane]      = o1;
    hf[(size_t)row * 128 + 64 + lane] = o2;
}

// ---------------- final GEMM: out = hf(16384x128) @ linW(128x349) + linb -----
__global__ __launch_bounds__(256) void k_gemm_out(const float* __restrict__ X,
                                                  const float* __restrict__ W,
                                                  const float* __restrict__ bias,
                                                  float* __restrict__ out) {
    __shared__ float Wl[128 * 64];
    __shared__ float Xl[64][33];
    const int tid = threadIdx.x;
    const int r0 = blockIdx.x * 64;
    const int c0 = blockIdx.y * 64;
    for (int idx = tid; idx < 128 * 64; idx += 256) {
        int k = idx >> 6, c = idx & 63;
        int gc = c0 + c;
        Wl[idx] = (gc < OUTD) ? W[(size_t)k * OUTD + gc] : 0.f;
    }
    float acc[16] = {0.f};
    const int rg = tid >> 2, h = tid & 3;
    for (int kc = 0; kc < 128; kc += 32) {
        __syncthreads();
        for (int idx = tid * 4; idx < 64 * 32; idx += 1024) {
            int row = idx >> 5, col = idx & 31;
            float4 v = *(const float4*)(X + (size_t)(r0 + row) * 128 + kc + col);
            Xl[row][col] = v.x; Xl[row][col + 1] = v.y;
            Xl[row][col + 2] = v.z; Xl[row][col + 3] = v.w;
        }
        __syncthreads();
        for (int kk = 0; kk < 32; ++kk) {
            float a = Xl[rg][kk];
            const float4* wr = (const float4*)(Wl + (kc + kk) * 64 + h * 16);
#pragma unroll
            for (int q = 0; q < 4; ++q) {
                float4 w = wr[q];
                acc[q * 4 + 0] += a * w.x; acc[q * 4 + 1] += a * w.y;
                acc[q * 4 + 2] += a * w.z; acc[q * 4 + 3] += a * w.w;
            }
        }
    }
    int n = r0 + rg;
#pragma unroll
    for (int q = 0; q < 16; ++q) {
        int c = c0 + h * 16 + q;
        if (c < OUTD) out[(size_t)n * OUTD + c] = acc[q] + bias[c];
    }
}

// ---------------- host ----------------
extern "C" void kernel_launch(void* const* d_in, const int* in_sizes, int n_in,
                              void* d_out, int out_size, void* d_ws, size_t ws_size,
                              hipStream_t stream) {
    const float* x_author = (const float*)d_in[0];
    const float* x_paper  = (const float*)d_in[1];
    const float* ntype    = (const float*)d_in[2];
    const float* W0  = (const float*)d_in[3];
    const float* al0 = (const float*)d_in[4];
    const float* ar0 = (const float*)d_in[5];
    const float* b0  = (const float*)d_in[6];
    const float* W1  = (const float*)d_in[7];
    const float* al1 = (const float*)d_in[8];
    const float* ar1 = (const float*)d_in[9];
    const float* b1  = (const float*)d_in[10];
    const float* ln1gb = (const float*)d_in[11];
    const float* attw  = (const float*)d_in[12];
    const float* attb  = (const float*)d_in[13];
    const float* ln2gb = (const float*)d_in[14];
    const float* fw1 = (const float*)d_in[15];
    const float* fb1 = (const float*)d_in[16];
    const float* fw2 = (const float*)d_in[17];
    const float* fb2 = (const float*)d_in[18];
    const float* linW = (const float*)d_in[19];
    const float* linb = (const float*)d_in[20];
    const int* srcW = (const int*)d_in[21];
    const int* dstW = (const int*)d_in[22];
    const int* srcC = (const int*)d_in[23];
    const int* dstC = (const int*)d_in[24];
    const int* srcR = (const int*)d_in[25];
    const int* dstR = (const int*)d_in[26];
    float* out = (float*)d_out;

    // ---- workspace carve-up ----
    float* ws = (float*)d_ws;
    size_t off = 0;
    float* fsW = ws + off; off += (size_t)N_A * HID;
    float* fsC = ws + off; off += (size_t)N_P * HID;
    float* fsR = ws + off; off += (size_t)N_P * HID;
    float* elw = ws + off; off += (size_t)N_A * NH;
    float* erw = ws + off; off += (size_t)N_P * NH;
    float* elc = ws + off; off += (size_t)N_P * NH;
    float* erc = ws + off; off += (size_t)N_P * NH;
    float* elr = ws + off; off += (size_t)N_P * NH;
    float* err = ws + off; off += (size_t)N_A * NH;
    float* oa0 = ws + off; off += (size_t)N_A * HID;
    float* op0 = ws + off; off += (size_t)N_P * HID;
    float* oa1 = ws + off; off += (size_t)N_A * HID;
    float* op1 = ws + off; off += (size_t)N_P * HID;
    float* hf  = ws + off; off += (size_t)N_P * 2 * HID;
    int* cnt  = (int*)(ws + off); off += 3 * 16384;
    int* row  = (int*)(ws + off); off += 3 * 16385 + 1;   // +1 keeps alignment slack
    int* cur  = (int*)(ws + off); off += 3 * 16384;
    int* esW  = (int*)(ws + off); off += NE;
    int* esC  = (int*)(ws + off); off += NE;
    int* esR  = (int*)(ws + off); off += NE;

    const int* rowW = row;
    const int* rowC = row + 16385;
    const int* rowR = row + 2 * 16385;

    const float* ntA = ntype;            // author scale row (128)
    const float* ntP = ntype + IN_D;     // paper scale row

    // ---- layer job tables (layer 0 reads raw x, scaled by NT on load) ----
    GemmJobs j0{};
    j0.X[0] = x_author; j0.W[0] = W0;                  j0.NT[0] = ntA;
    j0.F[0] = fsW; j0.EL[0] = elw; j0.ER[0] = nullptr; j0.AL[0] = al0;       j0.AR[0] = nullptr;
    j0.X[1] = x_paper;  j0.W[1] = W0;                  j0.NT[1] = ntP;
    j0.F[1] = nullptr; j0.EL[1] = nullptr; j0.ER[1] = erw; j0.AL[1] = nullptr; j0.AR[1] = ar0;
    j0.X[2] = x_paper;  j0.W[2] = W0 + IN_D * HID;     j0.NT[2] = ntP;
    j0.F[2] = fsC; j0.EL[2] = elc; j0.ER[2] = erc;     j0.AL[2] = al0 + 64;  j0.AR[2] = ar0 + 64;
    j0.X[3] = x_paper;  j0.W[3] = W0 + 2 * IN_D * HID; j0.NT[3] = ntP;
    j0.F[3] = fsR; j0.EL[3] = elr; j0.ER[3] = nullptr; j0.AL[3] = al0 + 128; j0.AR[3] = nullptr;
    j0.X[4] = x_author; j0.W[4] = W0 + 2 * IN_D * HID; j0.NT[4] = ntA;
    j0.F[4] = nullptr; j0.EL[4] = nullptr; j0.ER[4] = err; j0.AL[4] = nullptr; j0.AR[4] = ar0 + 128;

    GemmJobs j1{};
    j1.X[0] = oa0; j1.W[0] = W1;                   j1.NT[0] = nullptr;
    j1.F[0] = fsW; j1.EL[0] = elw; j1.ER[0] = nullptr; j1.AL[0] = al1;       j1.AR[0] = nullptr;
    j1.X[1] = op0; j1.W[1] = W1;                   j1.NT[1] = nullptr;
    j1.F[1] = nullptr; j1.EL[1] = nullptr; j1.ER[1] = erw; j1.AL[1] = nullptr; j1.AR[1] = ar1;
    j1.X[2] = op0; j1.W[2] = W1 + HID * HID;       j1.NT[2] = nullptr;
    j1.F[2] = fsC; j1.EL[2] = elc; j1.ER[2] = erc;     j1.AL[2] = al1 + 64;  j1.AR[2] = ar1 + 64;
    j1.X[3] = op0; j1.W[3] = W1 + 2 * HID * HID;   j1.NT[3] = nullptr;
    j1.F[3] = fsR; j1.EL[3] = elr; j1.ER[3] = nullptr; j1.AL[3] = al1 + 128; j1.AR[3] = nullptr;
    j1.X[4] = oa0; j1.W[4] = W1 + 2 * HID * HID;   j1.NT[4] = nullptr;
    j1.F[4] = nullptr; j1.EL[4] = nullptr; j1.ER[4] = err; j1.AL[4] = nullptr; j1.AR[4] = ar1 + 128;

    AggArgs a0{};
    a0.t[0] = {rowW, esW, elw, erw, fsW};
    a0.t[1] = {rowC, esC, elc, erc, fsC};
    a0.t[2] = {rowR, esR, elr, err, fsR};
    a0.b = b0; a0.op = op0; a0.oa = oa0;
    AggArgs a1 = a0;
    a1.b = b1; a1.op = op1; a1.oa = oa1;

    // ---- launches ----
    // CSR build (edge lists constant across layers)
    k_zero<<<(3 * 16384 + 255) / 256, 256, 0, stream>>>(cnt);
    k_hist<<<3 * NE / 256, 256, 0, stream>>>(dstW, dstC, dstR, cnt);
    k_scan<<<3, 1024, 0, stream>>>(cnt, row, cur);
    k_scatter<<<3 * NE / 256, 256, 0, stream>>>(srcW, dstW, srcC, dstC, srcR, dstR, cur, esW, esC, esR);

    // layer 0 (ntype scale folded into X load)
    k_gemm<IN_D, 0><<<dim3(N_A / 64, 1, 5), 256, 0, stream>>>(j0);
    k_agg<<<(N_P + N_A) / 4, 256, 0, stream>>>(a0);

    // layer 1 (relu folded into GEMM X loads)
    k_gemm<HID, 1><<<dim3(N_A / 64, 1, 5), 256, 0, stream>>>(j1);
    k_agg<<<(N_P + N_A) / 4, 256, 0, stream>>>(a1);

    // epilogue
    k_hf<<<N_P / 4, 256, 0, stream>>>(op1, hf, ln1gb, attw, attb, ln2gb, fw1, fb1, fw2, fb2);
    k_gemm_out<<<dim3(N_P / 64, (OUTD + 63) / 64), 256, 0, stream>>>(hf, linW, linb, out);
}

// Round 6
// 247.368 us; speedup vs baseline: 2.5757x; 1.2016x over previous
//
#include <hip/hip_runtime.h>
#include <math.h>

// ---------------- problem constants ----------------
constexpr int N_A   = 16384;
constexpr int N_P   = 16384;
constexpr int IN_D  = 128;
constexpr int HID   = 64;
constexpr int NH    = 4;    // heads
constexpr int OUTD  = 349;
constexpr int NE    = 262144; // edges per type (2^18)
constexpr float NEG = 0.2f;

__device__ __forceinline__ float lrelu(float x) { return x > 0.f ? x : NEG * x; }

// ---------------- CSR build (once per call; edge lists shared by both layers)
__global__ __launch_bounds__(256) void k_zero(int* __restrict__ cnt) {
    int i = blockIdx.x * 256 + threadIdx.x;
    if (i < 3 * 16384) cnt[i] = 0;
}

__global__ __launch_bounds__(256) void k_hist(const int* __restrict__ dW, const int* __restrict__ dC,
                                              const int* __restrict__ dR, int* __restrict__ cnt) {
    int idx = blockIdx.x * 256 + threadIdx.x;   // 3*NE
    int t = idx >> 18, i = idx & (NE - 1);
    const int* d = t == 0 ? dW : t == 1 ? dC : dR;
    atomicAdd(cnt + t * 16384 + d[i], 1);
}

__global__ __launch_bounds__(1024) void k_scan(const int* __restrict__ cnt, int* __restrict__ row,
                                               int* __restrict__ cur) {
    int b = blockIdx.x;                          // type
    const int* c = cnt + b * 16384;
    int* r = row + b * 16385;
    int* q = cur + b * 16384;
    __shared__ int part[1024];
    int t = threadIdx.x;
    int loc[16], s = 0;
#pragma unroll
    for (int i = 0; i < 16; ++i) { loc[i] = s; s += c[t * 16 + i]; }
    part[t] = s;
    __syncthreads();
    for (int w = 1; w < 1024; w <<= 1) {
        int v = (t >= w) ? part[t - w] : 0;
        __syncthreads();
        part[t] += v;
        __syncthreads();
    }
    int off = (t > 0) ? part[t - 1] : 0;
#pragma unroll
    for (int i = 0; i < 16; ++i) {
        int v = off + loc[i];
        r[t * 16 + i] = v;
        q[t * 16 + i] = v;
    }
    if (t == 1023) r[16384] = part[1023];
}

__global__ __launch_bounds__(256) void k_scatter(const int* __restrict__ sW, const int* __restrict__ dW,
                                                 const int* __restrict__ sC, const int* __restrict__ dC,
                                                 const int* __restrict__ sR, const int* __restrict__ dR,
                                                 int* __restrict__ cur,
                                                 int* __restrict__ eW, int* __restrict__ eC,
                                                 int* __restrict__ eR) {
    int idx = blockIdx.x * 256 + threadIdx.x;   // 3*NE
    int t = idx >> 18, i = idx & (NE - 1);
    const int* sp = t == 0 ? sW : t == 1 ? sC : sR;
    const int* dp = t == 0 ? dW : t == 1 ? dC : dR;
    int* ep = t == 0 ? eW : t == 1 ? eC : eR;
    int pos = atomicAdd(cur + t * 16384 + dp[i], 1);
    ep[pos] = sp[i];
}

// ---------------- batched GEMM (X@W) + el/er head reductions -------
// 4x4 register tile per thread (rows rg*4+i, cols tx*4+q); X staged
// TRANSPOSED (XT[k][row], pad 68 keeps b128 reads aligned+conflict-free);
// W staged in 32-k chunks. Per kk: 2x ds_read_b128 for 16 FMAs (was 5 DS
// instrs / 16 FMAs -> DS-issue bound, VALUBusy 18% — measured round 5).
// LDS 16.7 KB -> 8 blocks/CU.
struct GemmJobs {
    const float* X[5];  const float* W[5];  const float* NT[5];
    float* F[5];        float* EL[5];       float* ER[5];
    const float* AL[5]; const float* AR[5];
};

template <int K, int RELU>
__global__ __launch_bounds__(256) void k_gemm(GemmJobs j) {
    __shared__ float Wc[32 * 64];
    __shared__ float XT[32][68];

    const float* __restrict__ X;  const float* __restrict__ Wp;  const float* __restrict__ NTp;
    float* __restrict__ F;  float* __restrict__ EL;  float* __restrict__ ER;
    const float* __restrict__ AL; const float* __restrict__ AR;
    switch (blockIdx.z) {                         // block-uniform, static indices
      case 0: X=j.X[0]; Wp=j.W[0]; NTp=j.NT[0]; F=j.F[0]; EL=j.EL[0]; ER=j.ER[0]; AL=j.AL[0]; AR=j.AR[0]; break;
      case 1: X=j.X[1]; Wp=j.W[1]; NTp=j.NT[1]; F=j.F[1]; EL=j.EL[1]; ER=j.ER[1]; AL=j.AL[1]; AR=j.AR[1]; break;
      case 2: X=j.X[2]; Wp=j.W[2]; NTp=j.NT[2]; F=j.F[2]; EL=j.EL[2]; ER=j.ER[2]; AL=j.AL[2]; AR=j.AR[2]; break;
      case 3: X=j.X[3]; Wp=j.W[3]; NTp=j.NT[3]; F=j.F[3]; EL=j.EL[3]; ER=j.ER[3]; AL=j.AL[3]; AR=j.AR[3]; break;
      default: X=j.X[4]; Wp=j.W[4]; NTp=j.NT[4]; F=j.F[4]; EL=j.EL[4]; ER=j.ER[4]; AL=j.AL[4]; AR=j.AR[4]; break;
    }

    const int tid = threadIdx.x;
    const int tx  = tid & 15;     // col group: cols tx*4..tx*4+3
    const int rg  = tid >> 4;     // row group: rows rg*4..rg*4+3
    const int r0  = blockIdx.x * 64;

    float acc[4][4] = {};

    for (int kc = 0; kc < K; kc += 32) {
        __syncthreads();
        // stage W chunk (32x64)
#pragma unroll
        for (int it = 0; it < 2; ++it) {
            int idx = tid * 4 + it * 1024;
            int k = idx >> 6, c = idx & 63;
            *(float4*)(Wc + idx) = *(const float4*)(Wp + (size_t)(kc + k) * 64 + c);
        }
        // stage X chunk transposed (XT[k][row])
#pragma unroll
        for (int it = 0; it < 2; ++it) {
            int idx = tid * 4 + it * 1024;
            int row = idx >> 5, col = idx & 31;
            float4 v = *(const float4*)(X + (size_t)(r0 + row) * K + kc + col);
            if (RELU) {
                v.x = fmaxf(v.x, 0.f); v.y = fmaxf(v.y, 0.f);
                v.z = fmaxf(v.z, 0.f); v.w = fmaxf(v.w, 0.f);
            }
            if (NTp) {
                float4 s = *(const float4*)(NTp + kc + col);
                v.x *= s.x; v.y *= s.y; v.z *= s.z; v.w *= s.w;
            }
            XT[col + 0][row] = v.x;
            XT[col + 1][row] = v.y;
            XT[col + 2][row] = v.z;
            XT[col + 3][row] = v.w;
        }
        __syncthreads();
#pragma unroll
        for (int kk = 0; kk < 32; ++kk) {
            float4 a4 = *(const float4*)(&XT[kk][rg * 4]);
            float4 w4 = *(const float4*)(Wc + kk * 64 + tx * 4);
            acc[0][0] = fmaf(a4.x, w4.x, acc[0][0]); acc[0][1] = fmaf(a4.x, w4.y, acc[0][1]);
            acc[0][2] = fmaf(a4.x, w4.z, acc[0][2]); acc[0][3] = fmaf(a4.x, w4.w, acc[0][3]);
            acc[1][0] = fmaf(a4.y, w4.x, acc[1][0]); acc[1][1] = fmaf(a4.y, w4.y, acc[1][1]);
            acc[1][2] = fmaf(a4.y, w4.z, acc[1][2]); acc[1][3] = fmaf(a4.y, w4.w, acc[1][3]);
            acc[2][0] = fmaf(a4.z, w4.x, acc[2][0]); acc[2][1] = fmaf(a4.z, w4.y, acc[2][1]);
            acc[2][2] = fmaf(a4.z, w4.z, acc[2][2]); acc[2][3] = fmaf(a4.z, w4.w, acc[2][3]);
            acc[3][0] = fmaf(a4.w, w4.x, acc[3][0]); acc[3][1] = fmaf(a4.w, w4.y, acc[3][1]);
            acc[3][2] = fmaf(a4.w, w4.z, acc[3][2]); acc[3][3] = fmaf(a4.w, w4.w, acc[3][3]);
        }
    }

    if (F) {
#pragma unroll
        for (int i = 0; i < 4; ++i) {
            size_t n = (size_t)r0 + rg * 4 + i;
            *(float4*)(F + n * 64 + tx * 4) =
                make_float4(acc[i][0], acc[i][1], acc[i][2], acc[i][3]);
        }
    }
    // el/er: thread's 4 cols belong to head tx>>2; al slice for these cols is
    // AL[tx*4..tx*4+3] (tx*4 = head*16 + (tx&3)*4). Reduce over the 4 lanes of
    // the head group (lane bits 0,1) via shfl_xor.
    if (EL) {
        float4 alv = ((const float4*)AL)[tx];
#pragma unroll
        for (int i = 0; i < 4; ++i) {
            float p = acc[i][0] * alv.x + acc[i][1] * alv.y +
                      acc[i][2] * alv.z + acc[i][3] * alv.w;
            p += __shfl_xor(p, 1, 64);
            p += __shfl_xor(p, 2, 64);
            if ((tx & 3) == 0) EL[((size_t)r0 + rg * 4 + i) * 4 + (tx >> 2)] = p;
        }
    }
    if (ER) {
        float4 arv = ((const float4*)AR)[tx];
#pragma unroll
        for (int i = 0; i < 4; ++i) {
            float p = acc[i][0] * arv.x + acc[i][1] * arv.y +
                      acc[i][2] * arv.z + acc[i][3] * arv.w;
            p += __shfl_xor(p, 1, 64);
            p += __shfl_xor(p, 2, 64);
            if ((tx & 3) == 0) ER[((size_t)r0 + rg * 4 + i) * 4 + (tx >> 2)] = p;
        }
    }
}

// ---------------- per-destination gather aggregation (no atomics) ----------
// 16-edge chunks: lane l owns (edge l&15, head l>>4). One exp per lane per
// chunk; sn broadcast via readlane (uniform j), head weight via one shuffle.
// Normalization deferred: acc = sum(w * fs) then * 1/den.
struct AggType { const int* row; const int* es; const float* el; const float* er; const float* fs; };
struct AggArgs { AggType t[3]; const float* b; float* op; float* oa; };

__device__ __forceinline__ float agg16(const int* __restrict__ rowv, const int* __restrict__ es,
                                       const float* __restrict__ el, const float* __restrict__ er,
                                       const float* __restrict__ fs, int d, int lane) {
    int start = rowv[d], end = rowv[d + 1];
    int deg = end - start;
    if (deg <= 0) return 0.f;
    const int g = lane >> 4, j16 = lane & 15;
    const float rh = er[(size_t)d * 4 + g];
    const int nch = (deg + 15) >> 4;

    // pass 1: per-(edge,head) score max (within 16-lane group = per head)
    float m = -INFINITY;
    for (int c = 0; c < nch; ++c) {
        int o = c * 16 + j16;
        int sn = es[start + (o < deg ? o : 0)];
        float ev = lrelu(el[(size_t)sn * 4 + g] + rh);
        if (o < deg) m = fmaxf(m, ev);
    }
#pragma unroll
    for (int w = 1; w < 16; w <<= 1) m = fmaxf(m, __shfl_xor(m, w, 64));

    // pass 2: weights, denominator partials, unnormalized accumulation
    float den = 0.f, acc = 0.f;
    for (int c = 0; c < nch; ++c) {
        int o = c * 16 + j16;
        int sn = es[start + (o < deg ? o : 0)];
        float ev = (o < deg) ? lrelu(el[(size_t)sn * 4 + g] + rh) : -INFINITY;
        float wv = __expf(ev - m);          // 0 for padding slots
        den += wv;
#pragma unroll
        for (int jj = 0; jj < 16; ++jj) {
            int snj = __shfl(sn, jj, 64);                    // v_readlane (uniform)
            float wj = __shfl(wv, (lane & 48) + jj, 64);     // head-specific weight
            acc = fmaf(wj, fs[(size_t)snj * 64 + lane], acc);
        }
    }
#pragma unroll
    for (int w = 1; w < 16; w <<= 1) den += __shfl_xor(den, w, 64);
    return acc * (1.f / fmaxf(den, 1e-9f));
}

__global__ __launch_bounds__(256) void k_agg(AggArgs A) {
    int wid = (blockIdx.x * 256 + threadIdx.x) >> 6;  // one wave per dst node
    int lane = threadIdx.x & 63;
    if (wid < N_P) {
        // paper node: writes-GAT + cites-GAT (+ both biases)
        float acc = A.b[lane] + A.b[64 + lane];
        acc += agg16(A.t[0].row, A.t[0].es, A.t[0].el, A.t[0].er, A.t[0].fs, wid, lane);
        acc += agg16(A.t[1].row, A.t[1].es, A.t[1].el, A.t[1].er, A.t[1].fs, wid, lane);
        A.op[(size_t)wid * 64 + lane] = acc;
    } else {
        int d = wid - N_P;
        float acc = A.b[128 + lane];
        acc += agg16(A.t[2].row, A.t[2].es, A.t[2].el, A.t[2].er, A.t[2].fs, d, lane);
        A.oa[(size_t)d * 64 + lane] = acc;
    }
}

// ---------------- hf build: h2 = h1 + C, row l2-normalize, concat ------------
__global__ __launch_bounds__(256) void k_hf(const float* __restrict__ h1, float* __restrict__ hf,
                                            const float* __restrict__ ln1gb,
                                            const float* __restrict__ aw, const float* __restrict__ ab,
                                            const float* __restrict__ ln2gb,
                                            const float* __restrict__ fw1, const float* __restrict__ fb1,
                                            const float* __restrict__ fw2, const float* __restrict__ fb2) {
    __shared__ float Cs;
    if (threadIdx.x == 0) {
        // LN over size-1 axis -> exactly its bias term
        float y1 = ln1gb[1];
        float v  = y1 * aw[2] + ab[2];          // v constant; softmax uniform -> o = v
        float o  = v * aw[3] + ab[3];
        float y2 = ln2gb[1];
        float f  = fb2[0];
#pragma unroll
        for (int q = 0; q < 16; ++q) {
            float zz = y2 * fw1[q] + fb1[q];
            f += 0.5f * zz * (1.f + erff(zz * 0.70710678118654752f)) * fw2[q];
        }
        Cs = o + f;
    }
    __syncthreads();
    float C = Cs;
    int lane = threadIdx.x & 63;
    int row  = blockIdx.x * 4 + (threadIdx.x >> 6);
    float v1 = h1[(size_t)row * 64 + lane];
    float s1 = v1 * v1;
#pragma unroll
    for (int w = 1; w < 64; w <<= 1) s1 += __shfl_xor(s1, w, 64);
    float o1 = v1 / fmaxf(sqrtf(s1), 1e-12f);
    float v2 = v1 + C;
    float s2 = v2 * v2;
#pragma unroll
    for (int w = 1; w < 64; w <<= 1) s2 += __shfl_xor(s2, w, 64);
    float o2 = v2 / fmaxf(sqrtf(s2), 1e-12f);
    hf[(size_t)row * 128 + lane]      = o1;
    hf[(size_t)row * 128 + 64 + lane] = o2;
}

// ---------------- final GEMM: out = hf(16384x128) @ linW(128x349) + linb -----
// Same 4x4 register-tile structure as k_gemm (W chunked, XT transposed).
__global__ __launch_bounds__(256) void k_gemm_out(const float* __restrict__ X,
                                                  const float* __restrict__ W,
                                                  const float* __restrict__ bias,
                                                  float* __restrict__ out) {
    __shared__ float Wc[32 * 64];
    __shared__ float XT[32][68];
    const int tid = threadIdx.x;
    const int tx  = tid & 15;
    const int rg  = tid >> 4;
    const int r0  = blockIdx.x * 64;
    const int c0  = blockIdx.y * 64;

    float acc[4][4] = {};

    for (int kc = 0; kc < 128; kc += 32) {
        __syncthreads();
#pragma unroll
        for (int it = 0; it < 2; ++it) {
            int idx = tid * 4 + it * 1024;
            int k = idx >> 6, c = idx & 63;
            int gk = kc + k;
            float4 v;
            int gc = c0 + c;
            v.x = (gc + 0 < OUTD) ? W[(size_t)gk * OUTD + gc + 0] : 0.f;
            v.y = (gc + 1 < OUTD) ? W[(size_t)gk * OUTD + gc + 1] : 0.f;
            v.z = (gc + 2 < OUTD) ? W[(size_t)gk * OUTD + gc + 2] : 0.f;
            v.w = (gc + 3 < OUTD) ? W[(size_t)gk * OUTD + gc + 3] : 0.f;
            *(float4*)(Wc + idx) = v;
        }
#pragma unroll
        for (int it = 0; it < 2; ++it) {
            int idx = tid * 4 + it * 1024;
            int row = idx >> 5, col = idx & 31;
            float4 v = *(const float4*)(X + (size_t)(r0 + row) * 128 + kc + col);
            XT[col + 0][row] = v.x;
            XT[col + 1][row] = v.y;
            XT[col + 2][row] = v.z;
            XT[col + 3][row] = v.w;
        }
        __syncthreads();
#pragma unroll
        for (int kk = 0; kk < 32; ++kk) {
            float4 a4 = *(const float4*)(&XT[kk][rg * 4]);
            float4 w4 = *(const float4*)(Wc + kk * 64 + tx * 4);
            acc[0][0] = fmaf(a4.x, w4.x, acc[0][0]); acc[0][1] = fmaf(a4.x, w4.y, acc[0][1]);
            acc[0][2] = fmaf(a4.x, w4.z, acc[0][2]); acc[0][3] = fmaf(a4.x, w4.w, acc[0][3]);
            acc[1][0] = fmaf(a4.y, w4.x, acc[1][0]); acc[1][1] = fmaf(a4.y, w4.y, acc[1][1]);
            acc[1][2] = fmaf(a4.y, w4.z, acc[1][2]); acc[1][3] = fmaf(a4.y, w4.w, acc[1][3]);
            acc[2][0] = fmaf(a4.z, w4.x, acc[2][0]); acc[2][1] = fmaf(a4.z, w4.y, acc[2][1]);
            acc[2][2] = fmaf(a4.z, w4.z, acc[2][2]); acc[2][3] = fmaf(a4.z, w4.w, acc[2][3]);
            acc[3][0] = fmaf(a4.w, w4.x, acc[3][0]); acc[3][1] = fmaf(a4.w, w4.y, acc[3][1]);
            acc[3][2] = fmaf(a4.w, w4.z, acc[3][2]); acc[3][3] = fmaf(a4.w, w4.w, acc[3][3]);
        }
    }

    float b4[4];
#pragma unroll
    for (int q = 0; q < 4; ++q) {
        int c = c0 + tx * 4 + q;
        b4[q] = (c < OUTD) ? bias[c] : 0.f;
    }
#pragma unroll
    for (int i = 0; i < 4; ++i) {
        size_t n = (size_t)r0 + rg * 4 + i;
#pragma unroll
        for (int q = 0; q < 4; ++q) {
            int c = c0 + tx * 4 + q;
            if (c < OUTD) out[n * OUTD + c] = acc[i][q] + b4[q];
        }
    }
}

// ---------------- host ----------------
extern "C" void kernel_launch(void* const* d_in, const int* in_sizes, int n_in,
                              void* d_out, int out_size, void* d_ws, size_t ws_size,
                              hipStream_t stream) {
    const float* x_author = (const float*)d_in[0];
    const float* x_paper  = (const float*)d_in[1];
    const float* ntype    = (const float*)d_in[2];
    const float* W0  = (const float*)d_in[3];
    const float* al0 = (const float*)d_in[4];
    const float* ar0 = (const float*)d_in[5];
    const float* b0  = (const float*)d_in[6];
    const float* W1  = (const float*)d_in[7];
    const float* al1 = (const float*)d_in[8];
    const float* ar1 = (const float*)d_in[9];
    const float* b1  = (const float*)d_in[10];
    const float* ln1gb = (const float*)d_in[11];
    const float* attw  = (const float*)d_in[12];
    const float* attb  = (const float*)d_in[13];
    const float* ln2gb = (const float*)d_in[14];
    const float* fw1 = (const float*)d_in[15];
    const float* fb1 = (const float*)d_in[16];
    const float* fw2 = (const float*)d_in[17];
    const float* fb2 = (const float*)d_in[18];
    const float* linW = (const float*)d_in[19];
    const float* linb = (const float*)d_in[20];
    const int* srcW = (const int*)d_in[21];
    const int* dstW = (const int*)d_in[22];
    const int* srcC = (const int*)d_in[23];
    const int* dstC = (const int*)d_in[24];
    const int* srcR = (const int*)d_in[25];
    const int* dstR = (const int*)d_in[26];
    float* out = (float*)d_out;

    // ---- workspace carve-up ----
    float* ws = (float*)d_ws;
    size_t off = 0;
    float* fsW = ws + off; off += (size_t)N_A * HID;
    float* fsC = ws + off; off += (size_t)N_P * HID;
    float* fsR = ws + off; off += (size_t)N_P * HID;
    float* elw = ws + off; off += (size_t)N_A * NH;
    float* erw = ws + off; off += (size_t)N_P * NH;
    float* elc = ws + off; off += (size_t)N_P * NH;
    float* erc = ws + off; off += (size_t)N_P * NH;
    float* elr = ws + off; off += (size_t)N_P * NH;
    float* err = ws + off; off += (size_t)N_A * NH;
    float* oa0 = ws + off; off += (size_t)N_A * HID;
    float* op0 = ws + off; off += (size_t)N_P * HID;
    float* oa1 = ws + off; off += (size_t)N_A * HID;
    float* op1 = ws + off; off += (size_t)N_P * HID;
    float* hf  = ws + off; off += (size_t)N_P * 2 * HID;
    int* cnt  = (int*)(ws + off); off += 3 * 16384;
    int* row  = (int*)(ws + off); off += 3 * 16385 + 1;   // +1 keeps alignment slack
    int* cur  = (int*)(ws + off); off += 3 * 16384;
    int* esW  = (int*)(ws + off); off += NE;
    int* esC  = (int*)(ws + off); off += NE;
    int* esR  = (int*)(ws + off); off += NE;

    const int* rowW = row;
    const int* rowC = row + 16385;
    const int* rowR = row + 2 * 16385;

    const float* ntA = ntype;            // author scale row (128)
    const float* ntP = ntype + IN_D;     // paper scale row

    // ---- layer job tables (layer 0 reads raw x, scaled by NT on load) ----
    GemmJobs j0{};
    j0.X[0] = x_author; j0.W[0] = W0;                  j0.NT[0] = ntA;
    j0.F[0] = fsW; j0.EL[0] = elw; j0.ER[0] = nullptr; j0.AL[0] = al0;       j0.AR[0] = nullptr;
    j0.X[1] = x_paper;  j0.W[1] = W0;                  j0.NT[1] = ntP;
    j0.F[1] = nullptr; j0.EL[1] = nullptr; j0.ER[1] = erw; j0.AL[1] = nullptr; j0.AR[1] = ar0;
    j0.X[2] = x_paper;  j0.W[2] = W0 + IN_D * HID;     j0.NT[2] = ntP;
    j0.F[2] = fsC; j0.EL[2] = elc; j0.ER[2] = erc;     j0.AL[2] = al0 + 64;  j0.AR[2] = ar0 + 64;
    j0.X[3] = x_paper;  j0.W[3] = W0 + 2 * IN_D * HID; j0.NT[3] = ntP;
    j0.F[3] = fsR; j0.EL[3] = elr; j0.ER[3] = nullptr; j0.AL[3] = al0 + 128; j0.AR[3] = nullptr;
    j0.X[4] = x_author; j0.W[4] = W0 + 2 * IN_D * HID; j0.NT[4] = ntA;
    j0.F[4] = nullptr; j0.EL[4] = nullptr; j0.ER[4] = err; j0.AL[4] = nullptr; j0.AR[4] = ar0 + 128;

    GemmJobs j1{};
    j1.X[0] = oa0; j1.W[0] = W1;                   j1.NT[0] = nullptr;
    j1.F[0] = fsW; j1.EL[0] = elw; j1.ER[0] = nullptr; j1.AL[0] = al1;       j1.AR[0] = nullptr;
    j1.X[1] = op0; j1.W[1] = W1;                   j1.NT[1] = nullptr;
    j1.F[1] = nullptr; j1.EL[1] = nullptr; j1.ER[1] = erw; j1.AL[1] = nullptr; j1.AR[1] = ar1;
    j1.X[2] = op0; j1.W[2] = W1 + HID * HID;       j1.NT[2] = nullptr;
    j1.F[2] = fsC; j1.EL[2] = elc; j1.ER[2] = erc;     j1.AL[2] = al1 + 64;  j1.AR[2] = ar1 + 64;
    j1.X[3] = op0; j1.W[3] = W1 + 2 * HID * HID;   j1.NT[3] = nullptr;
    j1.F[3] = fsR; j1.EL[3] = elr; j1.ER[3] = nullptr; j1.AL[3] = al1 + 128; j1.AR[3] = nullptr;
    j1.X[4] = oa0; j1.W[4] = W1 + 2 * HID * HID;   j1.NT[4] = nullptr;
    j1.F[4] = nullptr; j1.EL[4] = nullptr; j1.ER[4] = err; j1.AL[4] = nullptr; j1.AR[4] = ar1 + 128;

    AggArgs a0{};
    a0.t[0] = {rowW, esW, elw, erw, fsW};
    a0.t[1] = {rowC, esC, elc, erc, fsC};
    a0.t[2] = {rowR, esR, elr, err, fsR};
    a0.b = b0; a0.op = op0; a0.oa = oa0;
    AggArgs a1 = a0;
    a1.b = b1; a1.op = op1; a1.oa = oa1;

    // ---- launches ----
    // CSR build (edge lists constant across layers)
    k_zero<<<(3 * 16384 + 255) / 256, 256, 0, stream>>>(cnt);
    k_hist<<<3 * NE / 256, 256, 0, stream>>>(dstW, dstC, dstR, cnt);
    k_scan<<<3, 1024, 0, stream>>>(cnt, row, cur);
    k_scatter<<<3 * NE / 256, 256, 0, stream>>>(srcW, dstW, srcC, dstC, srcR, dstR, cur, esW, esC, esR);

    // layer 0 (ntype scale folded into X load)
    k_gemm<IN_D, 0><<<dim3(N_A / 64, 1, 5), 256, 0, stream>>>(j0);
    k_agg<<<(N_P + N_A) / 4, 256, 0, stream>>>(a0);

    // layer 1 (relu folded into GEMM X loads)
    k_gemm<HID, 1><<<dim3(N_A / 64, 1, 5), 256, 0, stream>>>(j1);
    k_agg<<<(N_P + N_A) / 4, 256, 0, stream>>>(a1);

    // epilogue
    k_hf<<<N_P / 4, 256, 0, stream>>>(op1, hf, ln1gb, attw, attb, ln2gb, fw1, fb1, fw2, fb2);
    k_gemm_out<<<dim3(N_P / 64, (OUTD + 63) / 64), 256, 0, stream>>>(hf, linW, linb, out);
}